// Round 4
// baseline (596.686 us; speedup 1.0000x reference)
//
#include <hip/hip_runtime.h>
#include <math.h>

#define S_LEN 2048
#define HID 4096
#define NH 32
#define NKV 8
#define HD 128
#define NQKV 6144

typedef __bf16 bf16x8 __attribute__((ext_vector_type(8)));
typedef float f32x4 __attribute__((ext_vector_type(4)));
typedef short short8v __attribute__((ext_vector_type(8)));

__device__ inline short f2bf(float f) {
  union { float f; unsigned u; } a; a.f = f;
  unsigned r = a.u + 0x7fffu + ((a.u >> 16) & 1u);
  return (short)(r >> 16);
}

__device__ inline void glds16(const void* g, void* l) {
  __builtin_amdgcn_global_load_lds((const __attribute__((address_space(1))) void*)g,
                                   (__attribute__((address_space(3))) void*)l, 16, 0, 0);
}

template <int CTRL>
__device__ inline float dpp_max_step(float x) {
  int y = __builtin_amdgcn_update_dpp(0, __float_as_int(x), CTRL, 0xf, 0xf, false);
  return fmaxf(x, __int_as_float(y));
}

// ---------------- elementwise casts ----------------
__global__ __launch_bounds__(256) void cast_h(const float* __restrict__ X,
                                              short* __restrict__ Y, int n4) {
  int i = blockIdx.x * 256 + threadIdx.x;
  if (i >= n4) return;
  float4 v = ((const float4*)X)[i];
  short4 o;
  o.x = f2bf(v.x); o.y = f2bf(v.y); o.z = f2bf(v.z); o.w = f2bf(v.w);
  ((short4*)Y)[i] = o;
}

// W (4096 x Ncols) fp32 row-major  ->  Wt (Ncols x 4096) bf16
__global__ __launch_bounds__(256) void cast_wt(const float* __restrict__ W,
                                               short* __restrict__ Wt, int Ncols) {
  __shared__ float t[32][33];
  int n0 = blockIdx.x * 32, k0 = blockIdx.y * 32;
  int tx = threadIdx.x, ty = threadIdx.y;
  for (int j = 0; j < 4; j++)
    t[ty + 8 * j][tx] = W[(size_t)(k0 + ty + 8 * j) * Ncols + n0 + tx];
  __syncthreads();
  for (int j = 0; j < 4; j++)
    Wt[(size_t)(n0 + ty + 8 * j) * 4096 + k0 + tx] = f2bf(t[tx][ty + 8 * j]);
}

// ---------------- RoPE ----------------
__global__ void rope_table(const int* __restrict__ pos_ids, float* __restrict__ tc,
                           float* __restrict__ ts) {
  int p = blockIdx.x, i = threadIdx.x;
  float pos = (float)pos_ids[p];
  float inv = powf(10000.0f, -((float)(2 * i)) * (1.0f / 128.0f));
  float a = pos * inv;
  tc[p * 64 + i] = cosf(a);
  ts[p * 64 + i] = sinf(a);
}

// fused: apply RoPE to Q,K columns of C (in-place) + global absmax of Q,K,V
__global__ __launch_bounds__(256) void rope_absmax(float* __restrict__ C,
                                                   const float* __restrict__ tc,
                                                   const float* __restrict__ ts,
                                                   unsigned* __restrict__ scal) {
  __shared__ float lc[64], lsn[64];
  __shared__ float red[3][4];
  const int p = blockIdx.x, t = threadIdx.x;
  if (t < 64) { lc[t] = tc[p * 64 + t]; lsn[t] = ts[p * 64 + t]; }
  __syncthreads();
  float* row = C + (size_t)p * NQKV;
  float mq = 0.f, mk = 0.f, mv = 0.f;
#pragma unroll
  for (int j = 0; j < 8; j++) {  // Q: 32 heads x 64 = 2048 rotate-pairs
    int idx = t + 256 * j;
    int i = idx & 63, col = (idx >> 6) * 128 + i;
    float c = lc[i], s = lsn[i];
    float x1 = row[col], x2 = row[col + 64];
    float y1 = x1 * c - x2 * s, y2 = x2 * c + x1 * s;
    row[col] = y1; row[col + 64] = y2;
    mq = fmaxf(mq, fmaxf(fabsf(y1), fabsf(y2)));
  }
#pragma unroll
  for (int j = 0; j < 2; j++) {  // K: 8 heads x 64 = 512 rotate-pairs (j<2, NOT 4!)
    int idx = t + 256 * j;
    int i = idx & 63, col = 4096 + (idx >> 6) * 128 + i;
    float c = lc[i], s = lsn[i];
    float x1 = row[col], x2 = row[col + 64];
    float y1 = x1 * c - x2 * s, y2 = x2 * c + x1 * s;
    row[col] = y1; row[col + 64] = y2;
    mk = fmaxf(mk, fmaxf(fabsf(y1), fabsf(y2)));
  }
#pragma unroll
  for (int j = 0; j < 4; j++) {  // V: plain absmax over 1024 cols
    float v = row[5120 + t + 256 * j];
    mv = fmaxf(mv, fabsf(v));
  }
  for (int off = 32; off; off >>= 1) {
    mq = fmaxf(mq, __shfl_xor(mq, off, 64));
    mk = fmaxf(mk, __shfl_xor(mk, off, 64));
    mv = fmaxf(mv, __shfl_xor(mv, off, 64));
  }
  const int wave = t >> 6;
  if ((t & 63) == 0) { red[0][wave] = mq; red[1][wave] = mk; red[2][wave] = mv; }
  __syncthreads();
  if (t < 3) {
    float m = fmaxf(fmaxf(red[t][0], red[t][1]), fmaxf(red[t][2], red[t][3]));
    atomicMax(scal + t, __float_as_uint(m));
  }
}

// ---------------- quantize ----------------
__global__ __launch_bounds__(256) void quant_q(const float* __restrict__ C,
                                               const unsigned* __restrict__ scal,
                                               short* __restrict__ Qi) {
  int idx = blockIdx.x * 256 + threadIdx.x;
  float scale = __uint_as_float(scal[0]) * (1.0f / 127.0f);
  int p = idx >> 12, c = idx & 4095;
  Qi[idx] = f2bf(rintf(C[(size_t)p * NQKV + c] / scale));
}

__global__ __launch_bounds__(256) void quant_k(const float* __restrict__ C,
                                               const unsigned* __restrict__ scal,
                                               short* __restrict__ Ki) {
  int idx = blockIdx.x * 256 + threadIdx.x;
  float scale = __uint_as_float(scal[1]) * (1.0f / 127.0f);
  int h = idx >> 18, p = (idx >> 7) & 2047, d = idx & 127;
  Ki[idx] = f2bf(rintf(C[(size_t)p * NQKV + 4096 + h * 128 + d] / scale));
}

__global__ __launch_bounds__(256) void quant_vt(const float* __restrict__ C,
                                                const unsigned* __restrict__ scal,
                                                short* __restrict__ Vt) {
  __shared__ float t[64][65];
  int h = blockIdx.x, pt = blockIdx.y, dt = blockIdx.z;
  float scale = __uint_as_float(scal[2]) * (1.0f / 127.0f);
  int tid = threadIdx.x;
  for (int j = 0; j < 16; j++) {
    int q = tid + 256 * j;
    int pl = q >> 6, dl = q & 63;
    t[dl][pl] = C[(size_t)(pt * 64 + pl) * NQKV + 5120 + h * 128 + dt * 64 + dl];
  }
  __syncthreads();
  for (int j = 0; j < 16; j++) {
    int q = tid + 256 * j;
    int dl = q >> 6, pl = q & 63;
    Vt[(size_t)(h * 128 + dt * 64 + dl) * 2048 + pt * 64 + pl] =
        f2bf(rintf(t[dl][pl] / scale));
  }
}

// -- bf16 GEMM, C = A(MxK) * B^T(NxK): double-buffered glds16, 1 barrier/iter --
// (kept for the O-projection: 256^2 tiling would launch only 128 blocks there)
__global__ __launch_bounds__(256, 2) void gemm_bt(const short* __restrict__ A, int lda,
                                                  const short* __restrict__ B,
                                                  float* __restrict__ C, int ldc, int K) {
  __shared__ alignas(16) short As[2][4096];  // 128 rows x 32 (unpadded)
  __shared__ alignas(16) short Bs[2][4096];
  const int tid = threadIdx.x;
  const int wave = tid >> 6, lane = tid & 63;
  const int quad = lane >> 4, l15 = lane & 15;
  const int m0 = blockIdx.y * 128, n0 = blockIdx.x * 128;
  const int wm = (wave >> 1) * 64, wn = (wave & 1) * 64;
  f32x4 acc[4][4] = {};
  const int sr = wave * 16 + (lane >> 2);
  const int sg = (lane & 3) * 8;
  const short* Ag0 = A + (size_t)(m0 + sr) * lda + sg;
  const short* Ag1 = A + (size_t)(m0 + 64 + sr) * lda + sg;
  const short* Bg0 = B + (size_t)(n0 + sr) * K + sg;
  const short* Bg1 = B + (size_t)(n0 + 64 + sr) * K + sg;
  auto stage = [&](int kk, int b) {
    glds16(Ag0 + kk, &As[b][wave * 512]);
    glds16(Ag1 + kk, &As[b][2048 + wave * 512]);
    glds16(Bg0 + kk, &Bs[b][wave * 512]);
    glds16(Bg1 + kk, &Bs[b][2048 + wave * 512]);
  };
  stage(0, 0);
  int b = 0;
  for (int k0 = 0; k0 < K; k0 += 32) {
    __syncthreads();  // drains stage(k0) issued last iter; protects buf b^1
    const int nk = (k0 + 32 < K) ? k0 + 32 : k0;  // last iter: restage (unused)
    stage(nk, b ^ 1);
    bf16x8 af[4], bfr[4];
#pragma unroll
    for (int t = 0; t < 4; t++) {
      af[t] = *(const bf16x8*)&As[b][(wm + t * 16 + l15) * 32 + quad * 8];
      bfr[t] = *(const bf16x8*)&Bs[b][(wn + t * 16 + l15) * 32 + quad * 8];
    }
#pragma unroll
    for (int tm = 0; tm < 4; tm++)
#pragma unroll
      for (int tn = 0; tn < 4; tn++)
        acc[tm][tn] =
            __builtin_amdgcn_mfma_f32_16x16x32_bf16(af[tm], bfr[tn], acc[tm][tn], 0, 0, 0);
    b ^= 1;
  }
#pragma unroll
  for (int tm = 0; tm < 4; tm++)
#pragma unroll
    for (int tn = 0; tn < 4; tn++) {
      const int row = m0 + wm + tm * 16 + quad * 4;
      const int col = n0 + wn + tn * 16 + l15;
#pragma unroll
      for (int r = 0; r < 4; r++) C[(size_t)(row + r) * ldc + col] = acc[tm][tn][r];
    }
}

// -- 256x256 8-wave GEMM, 2-phase/K-tile with counted vmcnt (never 0):
//    BK=64, 2 LDS bufs (128 KiB), 2 barriers + 64 MFMA per K-tile.
//    Staging split: A(t+1) at tile top, B(t+2) post-B1 (into just-freed region).
//    FIFO vmcnt(4) drains exactly tile t+1's 8 loads, keeps B(t+2)'s 4 in flight.
//    XOR chunk-swizzle both sides, linear glds16 dest (rule #21).
//    C = A(MxK) * B^T(NxK).  Requires M%256==0, N%256==0, K%64==0, K>=128.
__global__ __launch_bounds__(512, 2) void gemm_bt8(const short* __restrict__ A, int lda,
                                                   const short* __restrict__ B, int ldb,
                                                   float* __restrict__ C, int ldc, int K) {
  __shared__ alignas(16) short As[2][16384];  // 256 rows x 64 k
  __shared__ alignas(16) short Bs[2][16384];
  const int tid = threadIdx.x;
  const int wave = tid >> 6, lane = tid & 63;
  const int quad = lane >> 4, l15 = lane & 15;
  const int wm = wave >> 2, wn = wave & 3;  // 2M x 4N waves; per-wave C = 128x64
  const int m0 = blockIdx.y * 256, n0 = blockIdx.x * 256;

  // Staging (per-wave sweep s covers tile rows s*64+wave*8 .. +8, 1 KiB linear LDS).
  // Lane l -> row = s*64 + wave*8 + (l>>3), source chunk c = (l&7) ^ (l>>3), so
  // LDS[row][c'] = G[row][c' ^ (row&7)]  (row&7 == l>>3 here).
  const int rsub = lane >> 3;
  const int csw = (lane & 7) ^ rsub;
  size_t asrc[4], bsrc[4];
#pragma unroll
  for (int s = 0; s < 4; s++) {
    int row = s * 64 + wave * 8 + rsub;
    asrc[s] = (size_t)(m0 + row) * lda + csw * 8;
    bsrc[s] = (size_t)(n0 + row) * ldb + csw * 8;
  }
  const int nt = K >> 6;

  auto stA = [&](int t2) {
    const int kk = (t2 < nt ? t2 : nt - 1) << 6;
#pragma unroll
    for (int s = 0; s < 4; s++)
      glds16(A + asrc[s] + kk, &As[t2 & 1][(s * 64 + wave * 8) * 64]);
  };
  auto stB = [&](int t2) {
    const int kk = (t2 < nt ? t2 : nt - 1) << 6;
#pragma unroll
    for (int s = 0; s < 4; s++)
      glds16(B + bsrc[s] + kk, &Bs[t2 & 1][(s * 64 + wave * 8) * 64]);
  };

  // Read-side swizzled offsets (shorts): row = base + l15, chunk = (kc*4+quad)^(l15&7)
  int swq[2];
#pragma unroll
  for (int kc = 0; kc < 2; kc++)
    swq[kc] = l15 * 64 + (((kc * 4 + quad) ^ (l15 & 7)) * 8);

  f32x4 acc[8][4] = {};

  // Prologue (matches loop invariant: entering t, buf[t&1] landed, B(t+1) in flight):
  stB(0); stA(0);  // tile 0
  stB(1);          // B of tile 1 (stays in flight across the wait)
  asm volatile("s_waitcnt vmcnt(4)" ::: "memory");  // drain tile 0's 8
  __builtin_amdgcn_s_barrier();

  for (int t = 0; t < nt; t++) {
    const short* Ab = As[t & 1];
    const short* Bb = Bs[t & 1];
    // ---- phase 1 (top): B-frag reads + A(t+1) staging ----
    stA(t + 1);  // -> As[(t+1)&1]; that region's readers finished last tile
    bf16x8 bfr[4][2];
#pragma unroll
    for (int n = 0; n < 4; n++) {
      bfr[n][0] = *(const bf16x8*)&Bb[(wn * 64 + n * 16) * 64 + swq[0]];
      bfr[n][1] = *(const bf16x8*)&Bb[(wn * 64 + n * 16) * 64 + swq[1]];
    }
    asm volatile("s_waitcnt lgkmcnt(0)" ::: "memory");  // my B-reads serviced
    __builtin_amdgcn_sched_barrier(0);
    __builtin_amdgcn_s_barrier();  // B1: all waves' B-reads done -> B region free
    // ---- phase 2: B(t+2) staging into freed region + A-stream MFMA ----
    stB(t + 2);  // -> Bs[t&1]; safe post-B1
    __builtin_amdgcn_s_setprio(1);
#pragma unroll
    for (int m = 0; m < 8; m++) {
      bf16x8 a0 = *(const bf16x8*)&Ab[(wm * 128 + m * 16) * 64 + swq[0]];
      bf16x8 a1 = *(const bf16x8*)&Ab[(wm * 128 + m * 16) * 64 + swq[1]];
#pragma unroll
      for (int n = 0; n < 4; n++) {
        acc[m][n] = __builtin_amdgcn_mfma_f32_16x16x32_bf16(a0, bfr[n][0], acc[m][n], 0, 0, 0);
        acc[m][n] = __builtin_amdgcn_mfma_f32_16x16x32_bf16(a1, bfr[n][1], acc[m][n], 0, 0, 0);
      }
    }
    __builtin_amdgcn_s_setprio(0);
    // FIFO: [B(t+1), A(t+1), B(t+2)] outstanding <=12; drain 8 = tile t+1 complete,
    // keep B(t+2)'s 4 in flight across the barrier (never drain to 0).
    asm volatile("s_waitcnt vmcnt(4)" ::: "memory");
    __builtin_amdgcn_s_barrier();  // B2: buf[(t+1)&1] published
    __builtin_amdgcn_sched_barrier(0);
  }
#pragma unroll
  for (int m = 0; m < 8; m++)
#pragma unroll
    for (int n = 0; n < 4; n++) {
      const int row = m0 + wm * 128 + m * 16 + quad * 4;
      const int col = n0 + wn * 64 + n * 16 + l15;
#pragma unroll
      for (int r = 0; r < 4; r++) C[(size_t)(row + r) * ldc + col] = acc[m][n][r];
    }
}

// ---- fused causal GQA attention: paired q-tiles, glds16 dbuf, XOR swizzle ----
__global__ __launch_bounds__(256, 2) void attn_fused(const short* __restrict__ Qi,
                                                     const short* __restrict__ Ki,
                                                     const short* __restrict__ Vt,
                                                     const unsigned* __restrict__ scal,
                                                     short* __restrict__ Oa) {
  __shared__ alignas(16) short Ks[2][64 * 128];   // [key][d], seg-swizzled
  __shared__ alignas(16) short Vs[2][128 * 64];   // [d][key], seg-swizzled
  __shared__ alignas(16) short Ps[4][16 * 72];    // per-wave P, padded
  const int tid = threadIdx.x;
  const int wave = tid >> 6, lane = tid & 63;
  const int quad = lane >> 4, l15 = lane & 15;
  const int swz = l15 & 7;
  const int h = blockIdx.x & 31, pq = blockIdx.x >> 5;
  const int kvh = h >> 2;
  const float qs = __uint_as_float(scal[0]) * (1.0f / 127.0f);
  const float ksc = __uint_as_float(scal[1]) * (1.0f / 127.0f);
  const float vsc = __uint_as_float(scal[2]) * (1.0f / 127.0f);
  const float sscale = qs * ksc * 0.08838834764831845f * 1.4426950408889634f;
  const short* Kg = Ki + (size_t)kvh * S_LEN * HD;
  const short* Vg = Vt + (size_t)kvh * HD * S_LEN;

  union { short8v s; bf16x8 b; } uone;
  uone.s = short8v{0x3F80, 0x3F80, 0x3F80, 0x3F80, 0x3F80, 0x3F80, 0x3F80, 0x3F80};
  const bf16x8 vone = uone.b;

  // staging slot -> swizzled global offsets (slot = j*256 + tid, 16B units)
  int koff[4], voff[4];
#pragma unroll
  for (int j = 0; j < 4; j++) {
    int slot = j * 256 + tid;
    int r = slot >> 4, seg = slot & 15;            // K: 64 rows x 16 segs
    koff[j] = r * 128 + ((seg ^ (r & 7)) * 8);
    int vr = slot >> 3, vseg = slot & 7;           // V: 128 rows x 8 segs
    voff[j] = vr * 2048 + ((vseg ^ (vr & 7)) * 8);
  }
  auto stage = [&](int k0, int b) {
#pragma unroll
    for (int j = 0; j < 4; j++)
      glds16(Kg + (size_t)k0 * HD + koff[j], &Ks[b][(j * 256 + wave * 64) * 8]);
#pragma unroll
    for (int j = 0; j < 4; j++)
      glds16(Vg + (size_t)k0 + voff[j], &Vs[b][(j * 256 + wave * 64) * 8]);
  };

  stage(0, 0);
  int buf = 0;
  for (int ph = 0; ph < 2; ph++) {
    const int qt = ph ? 31 - pq : pq;  // pair (i, 31-i): uniform 33 tiles/block
    const int rw = qt * 64 + wave * 16;
    bf16x8 aq[4];
#pragma unroll
    for (int kc = 0; kc < 4; kc++)
      aq[kc] = *(const bf16x8*)(Qi + (size_t)(rw + l15) * 4096 + h * 128 + kc * 32 +
                                quad * 8);
    f32x4 o[9] = {};
    float m_[4] = {-INFINITY, -INFINITY, -INFINITY, -INFINITY};
    const int nkt = qt + 1;
    for (int kt = 0; kt < nkt; kt++) {
      const int k0 = kt * 64;
      __syncthreads();  // drains current tile's glds16; protects buf^1
      const int nx = (kt + 1 < nkt) ? k0 + 64 : 0;  // next tile (or tile0 of next phase)
      stage(nx, buf ^ 1);

      const short* Kb = Ks[buf];
      const short* Vb = Vs[buf];
      f32x4 sf[4];
      __builtin_amdgcn_s_setprio(1);  // T5: favor QK^T MFMA cluster
#pragma unroll
      for (int tn = 0; tn < 4; tn++) {
        f32x4 s = {0.f, 0.f, 0.f, 0.f};
#pragma unroll
        for (int kc = 0; kc < 4; kc++) {
          bf16x8 bk = *(const bf16x8*)&Kb[(tn * 16 + l15) * 128 + ((kc * 4 + quad) ^ swz) * 8];
          s = __builtin_amdgcn_mfma_f32_16x16x32_bf16(aq[kc], bk, s, 0, 0, 0);
        }
        sf[tn] = s;
      }
      __builtin_amdgcn_s_setprio(0);

      const bool diag = (kt == qt);
#pragma unroll
      for (int r = 0; r < 4; r++) {
        const int grow = rw + quad * 4 + r;
        float mx = -3.0e38f;
        if (diag) {
#pragma unroll
          for (int tn = 0; tn < 4; tn++) {
            float v = sf[tn][r] * sscale;
            if (k0 + tn * 16 + l15 > grow) v = -3.0e38f;
            sf[tn][r] = v;
            mx = fmaxf(mx, v);
          }
        } else {
#pragma unroll
          for (int tn = 0; tn < 4; tn++) {
            float v = sf[tn][r] * sscale;
            sf[tn][r] = v;
            mx = fmaxf(mx, v);
          }
        }
        mx = dpp_max_step<0x121>(mx);
        mx = dpp_max_step<0x122>(mx);
        mx = dpp_max_step<0x124>(mx);
        mx = dpp_max_step<0x128>(mx);
        const float mo = m_[r];
        const float mn = fmaxf(mo, mx);
        m_[r] = mn;
        const float alpha = __builtin_amdgcn_exp2f(mo - mn);
#pragma unroll
        for (int tn = 0; tn < 4; tn++) {
          float p = __builtin_amdgcn_exp2f(sf[tn][r] - mn);
          Ps[wave][(quad * 4 + r) * 72 + tn * 16 + l15] =
              (short)((__float_as_uint(p) + 0x8000u) >> 16);
        }
        if (__ballot(alpha != 1.0f)) {
#pragma unroll
          for (int t = 0; t < 9; t++) o[t][r] *= alpha;
        }
      }
      // Ps wave-private; same-wave DS ordering suffices (verified round 2)
      __builtin_amdgcn_s_setprio(1);  // T5: favor PV MFMA cluster
#pragma unroll
      for (int kk = 0; kk < 2; kk++) {
        bf16x8 ap = *(const bf16x8*)&Ps[wave][l15 * 72 + kk * 32 + quad * 8];
#pragma unroll
        for (int tn = 0; tn < 8; tn++) {
          bf16x8 bv = *(const bf16x8*)&Vb[(tn * 16 + l15) * 64 + ((kk * 4 + quad) ^ swz) * 8];
          o[tn] = __builtin_amdgcn_mfma_f32_16x16x32_bf16(ap, bv, o[tn], 0, 0, 0);
        }
        o[8] = __builtin_amdgcn_mfma_f32_16x16x32_bf16(ap, vone, o[8], 0, 0, 0);  // l
      }
      __builtin_amdgcn_s_setprio(0);
      buf ^= 1;
    }
#pragma unroll
    for (int r = 0; r < 4; r++) {
      const int grow = rw + quad * 4 + r;
      const float sc = vsc / o[8][r];
#pragma unroll
      for (int tn = 0; tn < 8; tn++)
        Oa[(size_t)grow * 4096 + h * 128 + tn * 16 + l15] = f2bf(o[tn][r] * sc);
    }
  }
}

// ---------------- launch ----------------
extern "C" void kernel_launch(void* const* d_in, const int* in_sizes, int n_in,
                              void* d_out, int out_size, void* d_ws, size_t ws_size,
                              hipStream_t stream) {
  (void)in_sizes; (void)n_in; (void)out_size; (void)ws_size;
  const float* H  = (const float*)d_in[0];
  const int*   pos = (const int*)d_in[2];
  const float* wq = (const float*)d_in[3];
  const float* wk = (const float*)d_in[4];
  const float* wv = (const float*)d_in[5];
  const float* wo = (const float*)d_in[6];
  char* ws = (char*)d_ws;
  short* Hb   = (short*)(ws + 0);           // 16 MB
  short* Wt   = (short*)(ws + 16777216);    // 48 MB
  short* Wot  = (short*)(ws + 67108864);    // 32 MB
  float* C    = (float*)(ws + 100663296);   // 48 MB
  short* Qi   = (short*)(ws + 150994944);   // 16 MB
  short* Ki   = (short*)(ws + 167772160);   // 4 MB
  short* Vt   = (short*)(ws + 171966464);   // 4 MB
  short* Oa   = (short*)(ws + 176160768);   // 16 MB
  float* tc   = (float*)(ws + 192937984);   // 512 KB
  float* tsn  = (float*)(ws + 193462272);   // 512 KB
  unsigned* scal = (unsigned*)(ws + 193986560);

  hipLaunchKernelGGL(cast_h, dim3(8192), dim3(256), 0, stream, H, Hb, 2097152);
  hipLaunchKernelGGL(cast_wt, dim3(128, 128), dim3(32, 8), 0, stream, wq, Wt, 4096);
  hipLaunchKernelGGL(cast_wt, dim3(32, 128), dim3(32, 8), 0, stream, wk,
                     Wt + (size_t)4096 * 4096, 1024);
  hipLaunchKernelGGL(cast_wt, dim3(32, 128), dim3(32, 8), 0, stream, wv,
                     Wt + (size_t)5120 * 4096, 1024);
  hipLaunchKernelGGL(cast_wt, dim3(128, 128), dim3(32, 8), 0, stream, wo, Wot, 4096);
  hipLaunchKernelGGL(rope_table, dim3(2048), dim3(64), 0, stream, pos, tc, tsn);
  hipMemsetAsync(scal, 0, 16, stream);
  // QKV projection: 256^2 2-phase GEMM (192 blocks, 1 per CU)
  hipLaunchKernelGGL(gemm_bt8, dim3(24, 8), dim3(512), 0, stream, Hb, 4096, Wt, 4096, C,
                     6144, 4096);
  hipLaunchKernelGGL(rope_absmax, dim3(2048), dim3(256), 0, stream, C, tc, tsn, scal);
  hipLaunchKernelGGL(quant_q, dim3(32768), dim3(256), 0, stream, C, scal, Qi);
  hipLaunchKernelGGL(quant_k, dim3(8192), dim3(256), 0, stream, C, scal, Ki);
  hipLaunchKernelGGL(quant_vt, dim3(8, 32, 2), dim3(256), 0, stream, C, scal, Vt);
  hipLaunchKernelGGL(attn_fused, dim3(512), dim3(256), 0, stream, Qi, Ki, Vt, scal, Oa);
  hipLaunchKernelGGL(gemm_bt, dim3(32, 16), dim3(256), 0, stream, Oa, 4096, Wot,
                     (float*)d_out, 4096, 4096);
}

// Round 5
// 567.606 us; speedup vs baseline: 1.0512x; 1.0512x over previous
//
#include <hip/hip_runtime.h>
#include <math.h>

#define S_LEN 2048
#define HID 4096
#define NH 32
#define NKV 8
#define HD 128
#define NQKV 6144

typedef __bf16 bf16x8 __attribute__((ext_vector_type(8)));
typedef float f32x4 __attribute__((ext_vector_type(4)));
typedef short short8v __attribute__((ext_vector_type(8)));

__device__ inline short f2bf(float f) {
  union { float f; unsigned u; } a; a.f = f;
  unsigned r = a.u + 0x7fffu + ((a.u >> 16) & 1u);
  return (short)(r >> 16);
}

__device__ inline void glds16(const void* g, void* l) {
  __builtin_amdgcn_global_load_lds((const __attribute__((address_space(1))) void*)g,
                                   (__attribute__((address_space(3))) void*)l, 16, 0, 0);
}

template <int CTRL>
__device__ inline float dpp_max_step(float x) {
  int y = __builtin_amdgcn_update_dpp(0, __float_as_int(x), CTRL, 0xf, 0xf, false);
  return fmaxf(x, __int_as_float(y));
}

// ---------------- elementwise casts ----------------
__global__ __launch_bounds__(256) void cast_h(const float* __restrict__ X,
                                              short* __restrict__ Y, int n4) {
  int i = blockIdx.x * 256 + threadIdx.x;
  if (i >= n4) return;
  float4 v = ((const float4*)X)[i];
  short4 o;
  o.x = f2bf(v.x); o.y = f2bf(v.y); o.z = f2bf(v.z); o.w = f2bf(v.w);
  ((short4*)Y)[i] = o;
}

// W (4096 x Ncols) fp32 row-major  ->  Wt (Ncols x 4096) bf16
__global__ __launch_bounds__(256) void cast_wt(const float* __restrict__ W,
                                               short* __restrict__ Wt, int Ncols) {
  __shared__ float t[32][33];
  int n0 = blockIdx.x * 32, k0 = blockIdx.y * 32;
  int tx = threadIdx.x, ty = threadIdx.y;
  for (int j = 0; j < 4; j++)
    t[ty + 8 * j][tx] = W[(size_t)(k0 + ty + 8 * j) * Ncols + n0 + tx];
  __syncthreads();
  for (int j = 0; j < 4; j++)
    Wt[(size_t)(n0 + ty + 8 * j) * 4096 + k0 + tx] = f2bf(t[tx][ty + 8 * j]);
}

// ---------------- RoPE ----------------
__global__ void rope_table(const int* __restrict__ pos_ids, float* __restrict__ tc,
                           float* __restrict__ ts) {
  int p = blockIdx.x, i = threadIdx.x;
  float pos = (float)pos_ids[p];
  float inv = powf(10000.0f, -((float)(2 * i)) * (1.0f / 128.0f));
  float a = pos * inv;
  tc[p * 64 + i] = cosf(a);
  ts[p * 64 + i] = sinf(a);
}

// fused: apply RoPE to Q,K columns of C (in-place) + global absmax of Q,K,V
__global__ __launch_bounds__(256) void rope_absmax(float* __restrict__ C,
                                                   const float* __restrict__ tc,
                                                   const float* __restrict__ ts,
                                                   unsigned* __restrict__ scal) {
  __shared__ float lc[64], lsn[64];
  __shared__ float red[3][4];
  const int p = blockIdx.x, t = threadIdx.x;
  if (t < 64) { lc[t] = tc[p * 64 + t]; lsn[t] = ts[p * 64 + t]; }
  __syncthreads();
  float* row = C + (size_t)p * NQKV;
  float mq = 0.f, mk = 0.f, mv = 0.f;
#pragma unroll
  for (int j = 0; j < 8; j++) {  // Q: 32 heads x 64 = 2048 rotate-pairs
    int idx = t + 256 * j;
    int i = idx & 63, col = (idx >> 6) * 128 + i;
    float c = lc[i], s = lsn[i];
    float x1 = row[col], x2 = row[col + 64];
    float y1 = x1 * c - x2 * s, y2 = x2 * c + x1 * s;
    row[col] = y1; row[col + 64] = y2;
    mq = fmaxf(mq, fmaxf(fabsf(y1), fabsf(y2)));
  }
#pragma unroll
  for (int j = 0; j < 2; j++) {  // K: 8 heads x 64 = 512 rotate-pairs (j<2, NOT 4!)
    int idx = t + 256 * j;
    int i = idx & 63, col = 4096 + (idx >> 6) * 128 + i;
    float c = lc[i], s = lsn[i];
    float x1 = row[col], x2 = row[col + 64];
    float y1 = x1 * c - x2 * s, y2 = x2 * c + x1 * s;
    row[col] = y1; row[col + 64] = y2;
    mk = fmaxf(mk, fmaxf(fabsf(y1), fabsf(y2)));
  }
#pragma unroll
  for (int j = 0; j < 4; j++) {  // V: plain absmax over 1024 cols
    float v = row[5120 + t + 256 * j];
    mv = fmaxf(mv, fabsf(v));
  }
  for (int off = 32; off; off >>= 1) {
    mq = fmaxf(mq, __shfl_xor(mq, off, 64));
    mk = fmaxf(mk, __shfl_xor(mk, off, 64));
    mv = fmaxf(mv, __shfl_xor(mv, off, 64));
  }
  const int wave = t >> 6;
  if ((t & 63) == 0) { red[0][wave] = mq; red[1][wave] = mk; red[2][wave] = mv; }
  __syncthreads();
  if (t < 3) {
    float m = fmaxf(fmaxf(red[t][0], red[t][1]), fmaxf(red[t][2], red[t][3]));
    atomicMax(scal + t, __float_as_uint(m));
  }
}

// ---------------- quantize ----------------
__global__ __launch_bounds__(256) void quant_q(const float* __restrict__ C,
                                               const unsigned* __restrict__ scal,
                                               short* __restrict__ Qi) {
  int idx = blockIdx.x * 256 + threadIdx.x;
  float scale = __uint_as_float(scal[0]) * (1.0f / 127.0f);
  int p = idx >> 12, c = idx & 4095;
  Qi[idx] = f2bf(rintf(C[(size_t)p * NQKV + c] / scale));
}

__global__ __launch_bounds__(256) void quant_k(const float* __restrict__ C,
                                               const unsigned* __restrict__ scal,
                                               short* __restrict__ Ki) {
  int idx = blockIdx.x * 256 + threadIdx.x;
  float scale = __uint_as_float(scal[1]) * (1.0f / 127.0f);
  int h = idx >> 18, p = (idx >> 7) & 2047, d = idx & 127;
  Ki[idx] = f2bf(rintf(C[(size_t)p * NQKV + 4096 + h * 128 + d] / scale));
}

__global__ __launch_bounds__(256) void quant_vt(const float* __restrict__ C,
                                                const unsigned* __restrict__ scal,
                                                short* __restrict__ Vt) {
  __shared__ float t[64][65];
  int h = blockIdx.x, pt = blockIdx.y, dt = blockIdx.z;
  float scale = __uint_as_float(scal[2]) * (1.0f / 127.0f);
  int tid = threadIdx.x;
  for (int j = 0; j < 16; j++) {
    int q = tid + 256 * j;
    int pl = q >> 6, dl = q & 63;
    t[dl][pl] = C[(size_t)(pt * 64 + pl) * NQKV + 5120 + h * 128 + dt * 64 + dl];
  }
  __syncthreads();
  for (int j = 0; j < 16; j++) {
    int q = tid + 256 * j;
    int dl = q >> 6, pl = q & 63;
    Vt[(size_t)(h * 128 + dt * 64 + dl) * 2048 + pt * 64 + pl] =
        f2bf(rintf(t[dl][pl] / scale));
  }
}

// -- bf16 GEMM, C = A(MxK) * B^T(NxK): double-buffered glds16, 1 barrier/iter --
// (kept for the O-projection: 256^2 tiling would launch only 128 blocks there)
__global__ __launch_bounds__(256, 2) void gemm_bt(const short* __restrict__ A, int lda,
                                                  const short* __restrict__ B,
                                                  float* __restrict__ C, int ldc, int K) {
  __shared__ alignas(16) short As[2][4096];  // 128 rows x 32 (unpadded)
  __shared__ alignas(16) short Bs[2][4096];
  const int tid = threadIdx.x;
  const int wave = tid >> 6, lane = tid & 63;
  const int quad = lane >> 4, l15 = lane & 15;
  const int m0 = blockIdx.y * 128, n0 = blockIdx.x * 128;
  const int wm = (wave >> 1) * 64, wn = (wave & 1) * 64;
  f32x4 acc[4][4] = {};
  const int sr = wave * 16 + (lane >> 2);
  const int sg = (lane & 3) * 8;
  const short* Ag0 = A + (size_t)(m0 + sr) * lda + sg;
  const short* Ag1 = A + (size_t)(m0 + 64 + sr) * lda + sg;
  const short* Bg0 = B + (size_t)(n0 + sr) * K + sg;
  const short* Bg1 = B + (size_t)(n0 + 64 + sr) * K + sg;
  auto stage = [&](int kk, int b) {
    glds16(Ag0 + kk, &As[b][wave * 512]);
    glds16(Ag1 + kk, &As[b][2048 + wave * 512]);
    glds16(Bg0 + kk, &Bs[b][wave * 512]);
    glds16(Bg1 + kk, &Bs[b][2048 + wave * 512]);
  };
  stage(0, 0);
  int b = 0;
  for (int k0 = 0; k0 < K; k0 += 32) {
    __syncthreads();  // drains stage(k0) issued last iter; protects buf b^1
    const int nk = (k0 + 32 < K) ? k0 + 32 : k0;  // last iter: restage (unused)
    stage(nk, b ^ 1);
    bf16x8 af[4], bfr[4];
#pragma unroll
    for (int t = 0; t < 4; t++) {
      af[t] = *(const bf16x8*)&As[b][(wm + t * 16 + l15) * 32 + quad * 8];
      bfr[t] = *(const bf16x8*)&Bs[b][(wn + t * 16 + l15) * 32 + quad * 8];
    }
#pragma unroll
    for (int tm = 0; tm < 4; tm++)
#pragma unroll
      for (int tn = 0; tn < 4; tn++)
        acc[tm][tn] =
            __builtin_amdgcn_mfma_f32_16x16x32_bf16(af[tm], bfr[tn], acc[tm][tn], 0, 0, 0);
    b ^= 1;
  }
#pragma unroll
  for (int tm = 0; tm < 4; tm++)
#pragma unroll
    for (int tn = 0; tn < 4; tn++) {
      const int row = m0 + wm + tm * 16 + quad * 4;
      const int col = n0 + wn + tn * 16 + l15;
#pragma unroll
      for (int r = 0; r < 4; r++) C[(size_t)(row + r) * ldc + col] = acc[tm][tn][r];
    }
}

// -- 256x256 8-wave m201-faithful GEMM: BK=64, 2 LDS bufs, 8 phases / 2 K-steps,
//    1 half-tile (2 glds16) staged per phase, one vmcnt(4) per K-step (never 0),
//    explicit lgkmcnt(0) after the pre-MFMA barrier, setprio around MFMA cluster.
//    Staging map (iteration over K-steps tau, tau+1):
//      P1:A0(tau+1) P2:A1(tau+1) P3:B0(tau+2) P4:B1(tau+2)+vmcnt(4)
//      P5:A0(tau+2) P6:A1(tau+2) P7:B0(tau+3) P8:B1(tau+3)+vmcnt(4)
//    (B region of a buffer frees after its K-step's phase 1 -- B-frags are
//     register-cached; A region frees after phase 4.)  Hazard table verified.
//    XOR chunk-swizzle both sides, linear glds16 dest (rule #21).
//    C = A(MxK) * B^T(NxK).  Requires M%256==0, N%256==0, K%128==0.
__global__ __launch_bounds__(512, 2) void gemm_bt8(const short* __restrict__ A, int lda,
                                                   const short* __restrict__ B, int ldb,
                                                   float* __restrict__ C, int ldc, int K) {
  __shared__ alignas(16) short As[2][16384];  // [buf][256 rows][64 k]
  __shared__ alignas(16) short Bs[2][16384];
  const int tid = threadIdx.x;
  const int wave = tid >> 6, lane = tid & 63;
  const int quad = lane >> 4, l15 = lane & 15;
  const int wm = wave >> 2, wn = wave & 3;  // 2M x 4N waves; per-wave C = 128x64
  const int m0 = blockIdx.y * 256, n0 = blockIdx.x * 256;

  // glds16 call (h,g): rows h*128 + g*64 + wave*8 + rsub; linear LDS dest;
  // source chunk pre-swizzled: c = (l&7) ^ rsub  (rsub == row&7).
  const int rsub = lane >> 3;
  const int csw = (lane & 7) ^ rsub;
  size_t asrc[2][2], bsrc[2][2];
#pragma unroll
  for (int h = 0; h < 2; h++)
#pragma unroll
    for (int g = 0; g < 2; g++) {
      int row = h * 128 + g * 64 + wave * 8 + rsub;
      asrc[h][g] = (size_t)(m0 + row) * lda + csw * 8;
      bsrc[h][g] = (size_t)(n0 + row) * ldb + csw * 8;
    }
  const int nt = K >> 6;  // even

  // stage half-tile h of K-step tau (2 x glds16 = 16 KB block-wide)
  auto stH = [&](int tau, int isB, int h) {
    const int kk = (tau < nt ? tau : nt - 1) << 6;
    if (isB) {
#pragma unroll
      for (int g = 0; g < 2; g++)
        glds16(B + bsrc[h][g] + kk, &Bs[tau & 1][(h * 128 + g * 64 + wave * 8) * 64]);
    } else {
#pragma unroll
      for (int g = 0; g < 2; g++)
        glds16(A + asrc[h][g] + kk, &As[tau & 1][(h * 128 + g * 64 + wave * 8) * 64]);
    }
  };

  // Read-side swizzled offsets (shorts): row = base + l15, chunk = (kc*4+quad)^(l15&7)
  int swq[2];
#pragma unroll
  for (int kc = 0; kc < 2; kc++)
    swq[kc] = l15 * 64 + (((kc * 4 + quad) ^ (l15 & 7)) * 8);

  f32x4 acc[8][4] = {};

  auto ldA = [&](const short* Ab, int q, bf16x8* a) {
    a[0] = *(const bf16x8*)&Ab[(wm * 128 + (2 * q) * 16) * 64 + swq[0]];
    a[1] = *(const bf16x8*)&Ab[(wm * 128 + (2 * q) * 16) * 64 + swq[1]];
    a[2] = *(const bf16x8*)&Ab[(wm * 128 + (2 * q + 1) * 16) * 64 + swq[0]];
    a[3] = *(const bf16x8*)&Ab[(wm * 128 + (2 * q + 1) * 16) * 64 + swq[1]];
  };
  auto mfmaQ = [&](int q, bf16x8* a, bf16x8 (&bfr)[4][2]) {
    __builtin_amdgcn_s_setprio(1);
#pragma unroll
    for (int n = 0; n < 4; n++) {
      acc[2 * q][n] = __builtin_amdgcn_mfma_f32_16x16x32_bf16(a[0], bfr[n][0], acc[2 * q][n], 0, 0, 0);
      acc[2 * q][n] = __builtin_amdgcn_mfma_f32_16x16x32_bf16(a[1], bfr[n][1], acc[2 * q][n], 0, 0, 0);
      acc[2 * q + 1][n] = __builtin_amdgcn_mfma_f32_16x16x32_bf16(a[2], bfr[n][0], acc[2 * q + 1][n], 0, 0, 0);
      acc[2 * q + 1][n] = __builtin_amdgcn_mfma_f32_16x16x32_bf16(a[3], bfr[n][1], acc[2 * q + 1][n], 0, 0, 0);
    }
    __builtin_amdgcn_s_setprio(0);
  };

  // Prologue: K-step 0 complete + B halves of K-step 1; drain K-step 0's 8 loads.
  stH(0, 1, 0); stH(0, 1, 1); stH(0, 0, 0); stH(0, 0, 1);
  stH(1, 1, 0); stH(1, 1, 1);
  asm volatile("s_waitcnt vmcnt(4)" ::: "memory");
  __builtin_amdgcn_s_barrier();

  for (int t2 = 0; t2 < nt; t2 += 2) {
#pragma unroll
    for (int half = 0; half < 2; half++) {  // K-steps t2, t2+1
      const int tau = t2 + half;
      const short* Ab = As[tau & 1];
      const short* Bb = Bs[tau & 1];
      bf16x8 bfr[4][2], a[4];
      // ---- phase 1 of K-step: B-frags (8 reads) + A quadrant 0 (4 reads) ----
#pragma unroll
      for (int n = 0; n < 4; n++) {
        bfr[n][0] = *(const bf16x8*)&Bb[(wn * 64 + n * 16) * 64 + swq[0]];
        bfr[n][1] = *(const bf16x8*)&Bb[(wn * 64 + n * 16) * 64 + swq[1]];
      }
      ldA(Ab, 0, a);
      stH(tau + 1, 0, 0);  // A-h0 of next K-step
      asm volatile("s_waitcnt lgkmcnt(8)" ::: "memory");  // pace the 12-read phase
      __builtin_amdgcn_s_barrier();
      asm volatile("s_waitcnt lgkmcnt(0)" ::: "memory");
      mfmaQ(0, a, bfr);
      __builtin_amdgcn_s_barrier();
      // ---- phase 2: A quadrant 1 ----
      ldA(Ab, 1, a);
      stH(tau + 1, 0, 1);  // A-h1 of next K-step
      __builtin_amdgcn_s_barrier();
      asm volatile("s_waitcnt lgkmcnt(0)" ::: "memory");
      mfmaQ(1, a, bfr);
      __builtin_amdgcn_s_barrier();
      // ---- phase 3: A quadrant 2 ----
      ldA(Ab, 2, a);
      stH(tau + 2, 1, 0);  // B-h0 two K-steps ahead (region freed after phase 1)
      __builtin_amdgcn_s_barrier();
      asm volatile("s_waitcnt lgkmcnt(0)" ::: "memory");
      mfmaQ(2, a, bfr);
      __builtin_amdgcn_s_barrier();
      // ---- phase 4: A quadrant 3; K-step boundary wait ----
      ldA(Ab, 3, a);
      stH(tau + 2, 1, 1);  // B-h1 two K-steps ahead
      __builtin_amdgcn_s_barrier();
      asm volatile("s_waitcnt lgkmcnt(0)" ::: "memory");
      mfmaQ(3, a, bfr);
      // FIFO: drain next K-step's A halves (+prior B), keep 4 (B of tau+2) flying
      asm volatile("s_waitcnt vmcnt(4)" ::: "memory");
      __builtin_amdgcn_s_barrier();
    }
  }
#pragma unroll
  for (int m = 0; m < 8; m++)
#pragma unroll
    for (int n = 0; n < 4; n++) {
      const int row = m0 + wm * 128 + m * 16 + quad * 4;
      const int col = n0 + wn * 64 + n * 16 + l15;
#pragma unroll
      for (int r = 0; r < 4; r++) C[(size_t)(row + r) * ldc + col] = acc[m][n][r];
    }
}

// ---- fused causal GQA attention: paired q-tiles, glds16 dbuf, XOR swizzle ----
// (setprio removed this round: m190 lockstep evidence + round-3 arithmetic)
__global__ __launch_bounds__(256, 2) void attn_fused(const short* __restrict__ Qi,
                                                     const short* __restrict__ Ki,
                                                     const short* __restrict__ Vt,
                                                     const unsigned* __restrict__ scal,
                                                     short* __restrict__ Oa) {
  __shared__ alignas(16) short Ks[2][64 * 128];   // [key][d], seg-swizzled
  __shared__ alignas(16) short Vs[2][128 * 64];   // [d][key], seg-swizzled
  __shared__ alignas(16) short Ps[4][16 * 72];    // per-wave P, padded
  const int tid = threadIdx.x;
  const int wave = tid >> 6, lane = tid & 63;
  const int quad = lane >> 4, l15 = lane & 15;
  const int swz = l15 & 7;
  const int h = blockIdx.x & 31, pq = blockIdx.x >> 5;
  const int kvh = h >> 2;
  const float qs = __uint_as_float(scal[0]) * (1.0f / 127.0f);
  const float ksc = __uint_as_float(scal[1]) * (1.0f / 127.0f);
  const float vsc = __uint_as_float(scal[2]) * (1.0f / 127.0f);
  const float sscale = qs * ksc * 0.08838834764831845f * 1.4426950408889634f;
  const short* Kg = Ki + (size_t)kvh * S_LEN * HD;
  const short* Vg = Vt + (size_t)kvh * HD * S_LEN;

  union { short8v s; bf16x8 b; } uone;
  uone.s = short8v{0x3F80, 0x3F80, 0x3F80, 0x3F80, 0x3F80, 0x3F80, 0x3F80, 0x3F80};
  const bf16x8 vone = uone.b;

  // staging slot -> swizzled global offsets (slot = j*256 + tid, 16B units)
  int koff[4], voff[4];
#pragma unroll
  for (int j = 0; j < 4; j++) {
    int slot = j * 256 + tid;
    int r = slot >> 4, seg = slot & 15;            // K: 64 rows x 16 segs
    koff[j] = r * 128 + ((seg ^ (r & 7)) * 8);
    int vr = slot >> 3, vseg = slot & 7;           // V: 128 rows x 8 segs
    voff[j] = vr * 2048 + ((vseg ^ (vr & 7)) * 8);
  }
  auto stage = [&](int k0, int b) {
#pragma unroll
    for (int j = 0; j < 4; j++)
      glds16(Kg + (size_t)k0 * HD + koff[j], &Ks[b][(j * 256 + wave * 64) * 8]);
#pragma unroll
    for (int j = 0; j < 4; j++)
      glds16(Vg + (size_t)k0 + voff[j], &Vs[b][(j * 256 + wave * 64) * 8]);
  };

  stage(0, 0);
  int buf = 0;
  for (int ph = 0; ph < 2; ph++) {
    const int qt = ph ? 31 - pq : pq;  // pair (i, 31-i): uniform 33 tiles/block
    const int rw = qt * 64 + wave * 16;
    bf16x8 aq[4];
#pragma unroll
    for (int kc = 0; kc < 4; kc++)
      aq[kc] = *(const bf16x8*)(Qi + (size_t)(rw + l15) * 4096 + h * 128 + kc * 32 +
                                quad * 8);
    f32x4 o[9] = {};
    float m_[4] = {-INFINITY, -INFINITY, -INFINITY, -INFINITY};
    const int nkt = qt + 1;
    for (int kt = 0; kt < nkt; kt++) {
      const int k0 = kt * 64;
      __syncthreads();  // drains current tile's glds16; protects buf^1
      const int nx = (kt + 1 < nkt) ? k0 + 64 : 0;  // next tile (or tile0 of next phase)
      stage(nx, buf ^ 1);

      const short* Kb = Ks[buf];
      const short* Vb = Vs[buf];
      f32x4 sf[4];
#pragma unroll
      for (int tn = 0; tn < 4; tn++) {
        f32x4 s = {0.f, 0.f, 0.f, 0.f};
#pragma unroll
        for (int kc = 0; kc < 4; kc++) {
          bf16x8 bk = *(const bf16x8*)&Kb[(tn * 16 + l15) * 128 + ((kc * 4 + quad) ^ swz) * 8];
          s = __builtin_amdgcn_mfma_f32_16x16x32_bf16(aq[kc], bk, s, 0, 0, 0);
        }
        sf[tn] = s;
      }

      const bool diag = (kt == qt);
#pragma unroll
      for (int r = 0; r < 4; r++) {
        const int grow = rw + quad * 4 + r;
        float mx = -3.0e38f;
        if (diag) {
#pragma unroll
          for (int tn = 0; tn < 4; tn++) {
            float v = sf[tn][r] * sscale;
            if (k0 + tn * 16 + l15 > grow) v = -3.0e38f;
            sf[tn][r] = v;
            mx = fmaxf(mx, v);
          }
        } else {
#pragma unroll
          for (int tn = 0; tn < 4; tn++) {
            float v = sf[tn][r] * sscale;
            sf[tn][r] = v;
            mx = fmaxf(mx, v);
          }
        }
        mx = dpp_max_step<0x121>(mx);
        mx = dpp_max_step<0x122>(mx);
        mx = dpp_max_step<0x124>(mx);
        mx = dpp_max_step<0x128>(mx);
        const float mo = m_[r];
        const float mn = fmaxf(mo, mx);
        m_[r] = mn;
        const float alpha = __builtin_amdgcn_exp2f(mo - mn);
#pragma unroll
        for (int tn = 0; tn < 4; tn++) {
          float p = __builtin_amdgcn_exp2f(sf[tn][r] - mn);
          Ps[wave][(quad * 4 + r) * 72 + tn * 16 + l15] =
              (short)((__float_as_uint(p) + 0x8000u) >> 16);
        }
        if (__ballot(alpha != 1.0f)) {
#pragma unroll
          for (int t = 0; t < 9; t++) o[t][r] *= alpha;
        }
      }
      // Ps wave-private; same-wave DS ordering suffices (verified round 2)
#pragma unroll
      for (int kk = 0; kk < 2; kk++) {
        bf16x8 ap = *(const bf16x8*)&Ps[wave][l15 * 72 + kk * 32 + quad * 8];
#pragma unroll
        for (int tn = 0; tn < 8; tn++) {
          bf16x8 bv = *(const bf16x8*)&Vb[(tn * 16 + l15) * 64 + ((kk * 4 + quad) ^ swz) * 8];
          o[tn] = __builtin_amdgcn_mfma_f32_16x16x32_bf16(ap, bv, o[tn], 0, 0, 0);
        }
        o[8] = __builtin_amdgcn_mfma_f32_16x16x32_bf16(ap, vone, o[8], 0, 0, 0);  // l
      }
      buf ^= 1;
    }
#pragma unroll
    for (int r = 0; r < 4; r++) {
      const int grow = rw + quad * 4 + r;
      const float sc = vsc / o[8][r];
#pragma unroll
      for (int tn = 0; tn < 8; tn++)
        Oa[(size_t)grow * 4096 + h * 128 + tn * 16 + l15] = f2bf(o[tn][r] * sc);
    }
  }
}

// ---------------- launch ----------------
extern "C" void kernel_launch(void* const* d_in, const int* in_sizes, int n_in,
                              void* d_out, int out_size, void* d_ws, size_t ws_size,
                              hipStream_t stream) {
  (void)in_sizes; (void)n_in; (void)out_size; (void)ws_size;
  const float* H  = (const float*)d_in[0];
  const int*   pos = (const int*)d_in[2];
  const float* wq = (const float*)d_in[3];
  const float* wk = (const float*)d_in[4];
  const float* wv = (const float*)d_in[5];
  const float* wo = (const float*)d_in[6];
  char* ws = (char*)d_ws;
  short* Hb   = (short*)(ws + 0);           // 16 MB
  short* Wt   = (short*)(ws + 16777216);    // 48 MB
  short* Wot  = (short*)(ws + 67108864);    // 32 MB
  float* C    = (float*)(ws + 100663296);   // 48 MB
  short* Qi   = (short*)(ws + 150994944);   // 16 MB
  short* Ki   = (short*)(ws + 167772160);   // 4 MB
  short* Vt   = (short*)(ws + 171966464);   // 4 MB
  short* Oa   = (short*)(ws + 176160768);   // 16 MB
  float* tc   = (float*)(ws + 192937984);   // 512 KB
  float* tsn  = (float*)(ws + 193462272);   // 512 KB
  unsigned* scal = (unsigned*)(ws + 193986560);

  hipLaunchKernelGGL(cast_h, dim3(8192), dim3(256), 0, stream, H, Hb, 2097152);
  hipLaunchKernelGGL(cast_wt, dim3(128, 128), dim3(32, 8), 0, stream, wq, Wt, 4096);
  hipLaunchKernelGGL(cast_wt, dim3(32, 128), dim3(32, 8), 0, stream, wk,
                     Wt + (size_t)4096 * 4096, 1024);
  hipLaunchKernelGGL(cast_wt, dim3(32, 128), dim3(32, 8), 0, stream, wv,
                     Wt + (size_t)5120 * 4096, 1024);
  hipLaunchKernelGGL(cast_wt, dim3(128, 128), dim3(32, 8), 0, stream, wo, Wot, 4096);
  hipLaunchKernelGGL(rope_table, dim3(2048), dim3(64), 0, stream, pos, tc, tsn);
  hipMemsetAsync(scal, 0, 16, stream);
  // QKV projection: 256^2 m201-faithful 8-phase GEMM (192 blocks, 1 per CU)
  hipLaunchKernelGGL(gemm_bt8, dim3(24, 8), dim3(512), 0, stream, Hb, 4096, Wt, 4096, C,
                     6144, 4096);
  hipLaunchKernelGGL(rope_absmax, dim3(2048), dim3(256), 0, stream, C, tc, tsn, scal);
  hipLaunchKernelGGL(quant_q, dim3(32768), dim3(256), 0, stream, C, scal, Qi);
  hipLaunchKernelGGL(quant_k, dim3(8192), dim3(256), 0, stream, C, scal, Ki);
  hipLaunchKernelGGL(quant_vt, dim3(8, 32, 2), dim3(256), 0, stream, C, scal, Vt);
  hipLaunchKernelGGL(attn_fused, dim3(512), dim3(256), 0, stream, Qi, Ki, Vt, scal, Oa);
  hipLaunchKernelGGL(gemm_bt, dim3(32, 16), dim3(256), 0, stream, Oa, 4096, Wot,
                     (float*)d_out, 4096, 4096);
}